// Round 4
// baseline (311.571 us; speedup 1.0000x reference)
//
#include <hip/hip_runtime.h>

// MovingAverageLayer: x (T=262144, F=64) fp32 -> out (T, 4F) fp32
// out[:, 0:64]=x, out[:,64:128]=ma7, out[:,128:192]=ma30, out[:,192:256]=ma90
// (windowed mean for i>=p-1, expanding mean cumsum[i]/(i+1) for i<p-1)
//
// Round-3 structure (block-cooperative LDS + nontemporal stores, measured
// 305.3 us) plus XCD-chunked block swizzle:
//  - tile = (bid & 7) * 256 + (bid >> 3)  (bijective: 2048 % 8 == 0).
//    Hardware round-robins blockIdx across the 8 XCDs, so this gives each
//    XCD a CONTIGUOUS run of 256 tiles. Tile t's 90-row halo is the tail
//    of tile t-1's main stage; t-1 now runs on the SAME XCD (the block
//    launched 8 earlier), so the halo re-read is a same-XCD L2 hit
//    (64 resident blocks/XCD x 55.8 KB = 3.6 MB < 4 MB L2) instead of a
//    cross-die L3 fetch.
//  - Each block stages rows [base-90, base+128) (218 rows x 256 B =
//    55.8 KB) into LDS once, zero-filling the halo for tile 0.
//  - 512 threads = 8 strips x 64 cols, 16-row sliding scan per thread,
//    all window reads from LDS (2-way bank aliasing only = free).
//  - Nontemporal stores keep the 268 MB write-once output stream from
//    evicting the input tail out of L2 (round-3 win: -7.4 us).
//  - 55.8 KB LDS -> 2 blocks/CU -> 16 waves/CU (4/SIMD); 2048 blocks.

#define T_ROWS 262144
#define F_COLS 64
#define OUT_COLS 256
#define TILE 128                    // output rows per block
#define HALO 90
#define STAGE_ROWS (TILE + HALO)    // 218
#define THREADS 512
#define STRIPS 8                    // THREADS / 64
#define STRIP_ROWS (TILE / STRIPS)  // 16
#define N_TILES (T_ROWS / TILE)     // 2048
#define NXCD 8

__global__ __launch_bounds__(THREADS) void ma_kernel(const float* __restrict__ x,
                                                     float* __restrict__ out) {
    __shared__ float lds[STAGE_ROWS * F_COLS];   // 55808 B

    const int tid = threadIdx.x;
    // XCD-chunked swizzle: consecutive tiles -> same XCD (halo L2 locality)
    const int bid  = blockIdx.x;
    const int tile = (bid & (NXCD - 1)) * (N_TILES / NXCD) + (bid >> 3);
    const long base = (long)tile * TILE;

    // ---- stage rows [base-HALO, base+TILE) into LDS (zero-fill row < 0) ----
    {
        const long g0f = (base - HALO) * F_COLS;     // global float idx of lds[0]
        float4* lds4 = (float4*)lds;
        const int n4 = STAGE_ROWS * F_COLS / 4;      // 3488 float4s
        if (base >= HALO) {
            // fully in-range: contiguous 55.8 KB copy, coalesced float4
            const float4* __restrict__ src = (const float4*)(x + g0f);
            for (int idx = tid; idx < n4; idx += THREADS)
                lds4[idx] = src[idx];
        } else {
            // tile 0: rows below 0 -> zeros (boundary is float4-aligned:
            // g0f = -5760, so gf crosses 0 exactly at idx = 1440)
            for (int idx = tid; idx < n4; idx += THREADS) {
                long gf = g0f + (long)idx * 4;
                float4 v = make_float4(0.f, 0.f, 0.f, 0.f);
                if (gf >= 0) v = *(const float4*)(x + gf);
                lds4[idx] = v;
            }
        }
    }
    __syncthreads();

    // ---- sliding scan: strip = tid>>6 (wave-uniform), col = tid&63 ----
    const int col   = tid & 63;
    const int strip = tid >> 6;
    const int lr0   = HALO + strip * STRIP_ROWS;     // first local row of strip
    const long g0   = base + strip * STRIP_ROWS;     // first global row

    const float* __restrict__ lc = lds + col;        // column ptr, stride 64

    // warm-up: seed window sums from the 90 preceding (LDS) rows
    float s7 = 0.f, s30 = 0.f, s90 = 0.f;
    #pragma unroll
    for (int k = 1; k <= 7; ++k)  s7  += lc[(lr0 - k) * F_COLS];
    s30 = s7;
    #pragma unroll
    for (int k = 8; k <= 30; ++k) s30 += lc[(lr0 - k) * F_COLS];
    s90 = s30;
    #pragma unroll
    for (int k = 31; k <= 90; ++k) s90 += lc[(lr0 - k) * F_COLS];

    float* __restrict__ oc = out + col;

    if (g0 < 89) {
        // tile 0 only: rows gi <= 88 use expanding denominators min(gi+1, p)
        for (int j = 0; j < STRIP_ROWS; ++j) {
            const int lr = lr0 + j;
            const long gi = g0 + j;
            float v   = lc[lr * F_COLS];
            float o7  = lc[(lr - 7)  * F_COLS];
            float o30 = lc[(lr - 30) * F_COLS];
            float o90 = lc[(lr - 90) * F_COLS];
            s7 += v - o7; s30 += v - o30; s90 += v - o90;
            float fi  = (float)(gi + 1);
            float d7  = (gi < 6)  ? fi : 7.f;
            float d30 = (gi < 29) ? fi : 30.f;
            float d90 = (gi < 89) ? fi : 90.f;
            float* o = oc + gi * OUT_COLS;
            __builtin_nontemporal_store(v,         o);
            __builtin_nontemporal_store(s7  / d7,  o + 64);
            __builtin_nontemporal_store(s30 / d30, o + 128);
            __builtin_nontemporal_store(s90 / d90, o + 192);
        }
    } else {
        const float r7 = 1.f / 7.f, r30 = 1.f / 30.f, r90 = 1.f / 90.f;
        #pragma unroll
        for (int j = 0; j < STRIP_ROWS; ++j) {
            const int lr = lr0 + j;
            float v   = lc[lr * F_COLS];
            float o7  = lc[(lr - 7)  * F_COLS];
            float o30 = lc[(lr - 30) * F_COLS];
            float o90 = lc[(lr - 90) * F_COLS];
            s7 += v - o7; s30 += v - o30; s90 += v - o90;
            float* o = oc + (g0 + j) * OUT_COLS;
            __builtin_nontemporal_store(v,         o);
            __builtin_nontemporal_store(s7  * r7,  o + 64);
            __builtin_nontemporal_store(s30 * r30, o + 128);
            __builtin_nontemporal_store(s90 * r90, o + 192);
        }
    }
}

extern "C" void kernel_launch(void* const* d_in, const int* in_sizes, int n_in,
                              void* d_out, int out_size, void* d_ws, size_t ws_size,
                              hipStream_t stream) {
    const float* x = (const float*)d_in[0];
    float* out = (float*)d_out;
    ma_kernel<<<N_TILES, THREADS, 0, stream>>>(x, out);
}

// Round 5
// 306.431 us; speedup vs baseline: 1.0168x; 1.0168x over previous
//
#include <hip/hip_runtime.h>

// MovingAverageLayer: x (T=262144, F=64) fp32 -> out (T, 4F) fp32
// out[:, 0:64]=x, out[:,64:128]=ma7, out[:,128:192]=ma30, out[:,192:256]=ma90
// (windowed mean for i>=p-1, expanding mean cumsum[i]/(i+1) for i<p-1)
//
// Round-3 structure (block-cooperative LDS + nontemporal stores, measured
// 305.3 us; XCD swizzle REVERTED - regressed 6 us in round 4) with the
// tile doubled to cut halo re-read traffic:
//  - TILE=256, THREADS=1024: stage rows [base-90, base+256) = 346 rows
//    x 256 B = 88.6 KB LDS. Read amplification 1.35x (91 MB) vs 1.70x
//    (114 MB) at TILE=128.
//  - Occupancy unchanged in waves: 88.6 KB -> 1 block/CU x 16 waves
//    = 16 waves/CU (was 2 blocks x 8 waves).
//  - 16 strips x 64 cols, 16-row sliding scan per thread, all window
//    reads from LDS (2-way bank aliasing only = free). Zero-filled halo
//    for tile 0 makes windowed sum == cumsum diff everywhere; only the
//    denominators differ in the expanding region (gi < p-1).
//  - Nontemporal stores keep the 268 MB write-once output stream from
//    evicting cache (round-3 win: -7.4 us).

#define T_ROWS 262144
#define F_COLS 64
#define OUT_COLS 256
#define TILE 256                    // output rows per block
#define HALO 90
#define STAGE_ROWS (TILE + HALO)    // 346
#define THREADS 1024
#define STRIPS 16                   // THREADS / 64
#define STRIP_ROWS (TILE / STRIPS)  // 16
#define N_TILES (T_ROWS / TILE)     // 1024

__global__ __launch_bounds__(THREADS) void ma_kernel(const float* __restrict__ x,
                                                     float* __restrict__ out) {
    __shared__ float lds[STAGE_ROWS * F_COLS];   // 88576 B

    const int tid = threadIdx.x;
    const long base = (long)blockIdx.x * TILE;

    // ---- stage rows [base-HALO, base+TILE) into LDS (zero-fill row < 0) ----
    {
        const long g0f = (base - HALO) * F_COLS;     // global float idx of lds[0]
        float4* lds4 = (float4*)lds;
        const int n4 = STAGE_ROWS * F_COLS / 4;      // 5536 float4s
        if (base >= HALO) {
            // fully in-range: contiguous 88.6 KB copy, coalesced float4
            const float4* __restrict__ src = (const float4*)(x + g0f);
            for (int idx = tid; idx < n4; idx += THREADS)
                lds4[idx] = src[idx];
        } else {
            // tile 0: rows below 0 -> zeros (boundary is float4-aligned:
            // g0f = -5760, so gf crosses 0 exactly at idx = 1440)
            for (int idx = tid; idx < n4; idx += THREADS) {
                long gf = g0f + (long)idx * 4;
                float4 v = make_float4(0.f, 0.f, 0.f, 0.f);
                if (gf >= 0) v = *(const float4*)(x + gf);
                lds4[idx] = v;
            }
        }
    }
    __syncthreads();

    // ---- sliding scan: strip = tid>>6 (wave-uniform), col = tid&63 ----
    const int col   = tid & 63;
    const int strip = tid >> 6;
    const int lr0   = HALO + strip * STRIP_ROWS;     // first local row of strip
    const long g0   = base + strip * STRIP_ROWS;     // first global row

    const float* __restrict__ lc = lds + col;        // column ptr, stride 64

    // warm-up: seed window sums from the 90 preceding (LDS) rows
    float s7 = 0.f, s30 = 0.f, s90 = 0.f;
    #pragma unroll
    for (int k = 1; k <= 7; ++k)  s7  += lc[(lr0 - k) * F_COLS];
    s30 = s7;
    #pragma unroll
    for (int k = 8; k <= 30; ++k) s30 += lc[(lr0 - k) * F_COLS];
    s90 = s30;
    #pragma unroll
    for (int k = 31; k <= 90; ++k) s90 += lc[(lr0 - k) * F_COLS];

    float* __restrict__ oc = out + col;

    if (g0 < 89) {
        // tile 0 only: rows gi <= 88 use expanding denominators min(gi+1, p)
        for (int j = 0; j < STRIP_ROWS; ++j) {
            const int lr = lr0 + j;
            const long gi = g0 + j;
            float v   = lc[lr * F_COLS];
            float o7  = lc[(lr - 7)  * F_COLS];
            float o30 = lc[(lr - 30) * F_COLS];
            float o90 = lc[(lr - 90) * F_COLS];
            s7 += v - o7; s30 += v - o30; s90 += v - o90;
            float fi  = (float)(gi + 1);
            float d7  = (gi < 6)  ? fi : 7.f;
            float d30 = (gi < 29) ? fi : 30.f;
            float d90 = (gi < 89) ? fi : 90.f;
            float* o = oc + gi * OUT_COLS;
            __builtin_nontemporal_store(v,         o);
            __builtin_nontemporal_store(s7  / d7,  o + 64);
            __builtin_nontemporal_store(s30 / d30, o + 128);
            __builtin_nontemporal_store(s90 / d90, o + 192);
        }
    } else {
        const float r7 = 1.f / 7.f, r30 = 1.f / 30.f, r90 = 1.f / 90.f;
        #pragma unroll
        for (int j = 0; j < STRIP_ROWS; ++j) {
            const int lr = lr0 + j;
            float v   = lc[lr * F_COLS];
            float o7  = lc[(lr - 7)  * F_COLS];
            float o30 = lc[(lr - 30) * F_COLS];
            float o90 = lc[(lr - 90) * F_COLS];
            s7 += v - o7; s30 += v - o30; s90 += v - o90;
            float* o = oc + (g0 + j) * OUT_COLS;
            __builtin_nontemporal_store(v,         o);
            __builtin_nontemporal_store(s7  * r7,  o + 64);
            __builtin_nontemporal_store(s30 * r30, o + 128);
            __builtin_nontemporal_store(s90 * r90, o + 192);
        }
    }
}

extern "C" void kernel_launch(void* const* d_in, const int* in_sizes, int n_in,
                              void* d_out, int out_size, void* d_ws, size_t ws_size,
                              hipStream_t stream) {
    const float* x = (const float*)d_in[0];
    float* out = (float*)d_out;
    ma_kernel<<<N_TILES, THREADS, 0, stream>>>(x, out);
}